// Round 5
// baseline (661.229 us; speedup 1.0000x reference)
//
#include <hip/hip_runtime.h>
#include <hip/hip_bf16.h>

constexpr int D = 256;   // dim_h
constexpr int PG = 1024; // nodes per graph

typedef __attribute__((ext_vector_type(8))) short bf16x8;  // 8 bf16 in 4 VGPRs
typedef __attribute__((ext_vector_type(4))) float f32x4;

__device__ inline short f2bf(float f) {
    __hip_bfloat16 h = __float2bfloat16(f);
    return *reinterpret_cast<short*>(&h);
}
__device__ inline float bf2f(short s) {
    return __uint_as_float(((unsigned)(unsigned short)s) << 16);
}

// ===========================================================================
// weights f32 -> bf16 (all six fused; element/8 prefixes hardcoded for D=256)
// ===========================================================================
__global__ __launch_bounds__(256) void cvt_weights(
    const float* __restrict__ w1, const float* __restrict__ w2,
    const float* __restrict__ w3, const float* __restrict__ w4,
    const float* __restrict__ w5, const float* __restrict__ w6,
    short* __restrict__ out)
{
    int i = blockIdx.x * 256 + threadIdx.x;   // [0, 81920)
    const float* src; int base;
    if (i < 16384)      { if (i < 8192) { src = w1; base = 0; }
                          else          { src = w2; base = 8192; } }
    else if (i < 40960) { src = w3; base = 16384; }
    else if (i < 49152) { src = w4; base = 40960; }
    else if (i < 65536) { src = w5; base = 49152; }
    else                { src = w6; base = 65536; }
    int k = i - base;
    float4 a = ((const float4*)src)[k * 2];
    float4 b = ((const float4*)src)[k * 2 + 1];
    bf16x8 v;
    v[0] = f2bf(a.x); v[1] = f2bf(a.y); v[2] = f2bf(a.z); v[3] = f2bf(a.w);
    v[4] = f2bf(b.x); v[5] = f2bf(b.y); v[6] = f2bf(b.z); v[7] = f2bf(b.w);
    ((bf16x8*)out)[i] = v;
}

// ===========================================================================
// CSR build: histogram -> 2-level exclusive scan -> scatter
// ===========================================================================
__global__ __launch_bounds__(256) void hist_kernel(
    const int* __restrict__ dst, int* __restrict__ cnt, int E)
{
    int e = blockIdx.x * 256 + threadIdx.x;
    if (e < E) atomicAdd(&cnt[dst[e]], 1);
}

__global__ __launch_bounds__(256) void scan_block(
    const int* __restrict__ cnt, int* __restrict__ excl, int* __restrict__ bsum)
{
    __shared__ int sm[256];
    const int t = threadIdx.x;
    const int i = blockIdx.x * 256 + t;
    int v = cnt[i];
    sm[t] = v;
    __syncthreads();
    #pragma unroll
    for (int o = 1; o < 256; o <<= 1) {
        int u = (t >= o) ? sm[t - o] : 0;
        __syncthreads();
        sm[t] += u;
        __syncthreads();
    }
    excl[i] = sm[t] - v;
    if (t == 255) bsum[blockIdx.x] = sm[255];
}

__global__ __launch_bounds__(128) void scan_bsum(int* __restrict__ bsum)
{
    __shared__ int sm[128];
    const int t = threadIdx.x;
    int v = bsum[t];
    sm[t] = v;
    __syncthreads();
    #pragma unroll
    for (int o = 1; o < 128; o <<= 1) {
        int u = (t >= o) ? sm[t - o] : 0;
        __syncthreads();
        sm[t] += u;
        __syncthreads();
    }
    bsum[t] = sm[t] - v;
}

__global__ __launch_bounds__(256) void scan_add(
    const int* __restrict__ excl, const int* __restrict__ bsum,
    int* __restrict__ rowptr, int* __restrict__ ofs)
{
    int i = blockIdx.x * 256 + threadIdx.x;
    int r = excl[i] + bsum[blockIdx.x];
    rowptr[i] = r;
    ofs[i] = r;
}

__global__ __launch_bounds__(256) void scatter_kernel(
    const int* __restrict__ src, const int* __restrict__ dst,
    int* __restrict__ ofs, int* __restrict__ eord, int* __restrict__ esrc, int E)
{
    int e = blockIdx.x * 256 + threadIdx.x;
    if (e >= E) return;
    int d = dst[e];
    int pos = atomicAdd(&ofs[d], 1);
    eord[pos] = e;
    esrc[pos] = src[e];
}

// ===========================================================================
// CSR aggregation -> bf16 Z. One wave per dst node.
// ===========================================================================
__global__ __launch_bounds__(256) void csr_aggr(
    const float* __restrict__ x, const float* __restrict__ ea,
    const int* __restrict__ rowptr, const int* __restrict__ cnt,
    const int* __restrict__ eord, const int* __restrict__ esrc,
    short* __restrict__ z)
{
    int gid = blockIdx.x * 256 + threadIdx.x;
    int node = gid >> 6;
    int c = (gid & 63) << 2;
    int start = rowptr[node];
    int deg = cnt[node];
    float4 acc = *(const float4*)(x + (size_t)node * D + c);
    for (int i = 0; i < deg; ++i) {
        int e = eord[start + i];
        int s = esrc[start + i];
        float4 xa = *(const float4*)(x + (size_t)s * D + c);
        float4 av = *(const float4*)(ea + (size_t)e * D + c);
        acc.x += fmaxf(xa.x + av.x, 0.f);
        acc.y += fmaxf(xa.y + av.y, 0.f);
        acc.z += fmaxf(xa.z + av.z, 0.f);
        acc.w += fmaxf(xa.w + av.w, 0.f);
    }
    short4 r;
    r.x = f2bf(acc.x); r.y = f2bf(acc.y); r.z = f2bf(acc.z); r.w = f2bf(acc.w);
    *(short4*)(z + (size_t)node * D + c) = r;
}

// ===========================================================================
// MFMA bf16 GEMM: Y(bf16) = relu?(X @ W^T + bias) (+ addf/addb), fused BN stats.
// Tile 128x128, BK=64, 4 waves. Epilogue: LDS transpose -> coalesced bf16x8
// stores + vectorized residual add + per-column sum/sumsq (shfl + atomics).
// ===========================================================================
template<bool XF32, bool RELU, bool ADDF, bool ADDB, bool STATS>
__global__ __launch_bounds__(256) void gemm_mfma(
    const short* __restrict__ X, const float* __restrict__ Xf,
    const short* __restrict__ W, const float* __restrict__ bias,
    const float* __restrict__ addf, const short* __restrict__ addb,
    short* __restrict__ Y, float* __restrict__ st, int K, int M)
{
    __shared__ __align__(16) short SH[2][128 * 72];

    const int nbx = gridDim.x;
    const int nwg = nbx * gridDim.y;
    const int bid = blockIdx.y * nbx + blockIdx.x;
    const int cpx = nwg >> 3;                     // all grids are %8 == 0
    const int wg  = (bid & 7) * cpx + (bid >> 3);
    const int r0 = (wg / nbx) * 128;
    const int c0 = (wg % nbx) * 128;

    const int t = threadIdx.x, w = t >> 6, l = t & 63;
    const int wr = w >> 1, wc = w & 1, lg = l >> 4, lm = l & 15;
    const int srow = t >> 3;            // staging row 0..31
    const int scol = (t & 7) * 8;       // staging col 0..56

    f32x4 acc[4][4];
    #pragma unroll
    for (int i = 0; i < 4; ++i)
        #pragma unroll
        for (int j = 0; j < 4; ++j)
            acc[i][j] = (f32x4){0.f, 0.f, 0.f, 0.f};

    for (int k0 = 0; k0 < K; k0 += 64) {
        __syncthreads();
        #pragma unroll
        for (int it = 0; it < 4; ++it) {
            int r = it * 32 + srow;
            bf16x8 xv;
            if (XF32) {
                const float* p = Xf + (size_t)(r0 + r) * K + k0 + scol;
                float4 a = *(const float4*)p;
                float4 b = *(const float4*)(p + 4);
                xv[0] = f2bf(a.x); xv[1] = f2bf(a.y); xv[2] = f2bf(a.z); xv[3] = f2bf(a.w);
                xv[4] = f2bf(b.x); xv[5] = f2bf(b.y); xv[6] = f2bf(b.z); xv[7] = f2bf(b.w);
            } else {
                xv = *(const bf16x8*)(X + (size_t)(r0 + r) * K + k0 + scol);
            }
            bf16x8 wv = *(const bf16x8*)(W + (size_t)(c0 + r) * K + k0 + scol);
            *(bf16x8*)&SH[0][r * 72 + scol] = xv;
            *(bf16x8*)&SH[1][r * 72 + scol] = wv;
        }
        __syncthreads();

        bf16x8 af[4][2], bfr[4][2];
        #pragma unroll
        for (int i = 0; i < 4; ++i)
            #pragma unroll
            for (int ks = 0; ks < 2; ++ks) {
                af[i][ks]  = *(const bf16x8*)&SH[0][(wr*64 + i*16 + lm)*72 + ks*32 + lg*8];
                bfr[i][ks] = *(const bf16x8*)&SH[1][(wc*64 + i*16 + lm)*72 + ks*32 + lg*8];
            }
        #pragma unroll
        for (int i = 0; i < 4; ++i)
            #pragma unroll
            for (int j = 0; j < 4; ++j) {
                acc[i][j] = __builtin_amdgcn_mfma_f32_16x16x32_bf16(af[i][0], bfr[j][0], acc[i][j], 0, 0, 0);
                acc[i][j] = __builtin_amdgcn_mfma_f32_16x16x32_bf16(af[i][1], bfr[j][1], acc[i][j], 0, 0, 0);
            }
    }

    // ---- epilogue: bias/relu -> LDS (wave-private 64x72) -> transpose read ----
    __syncthreads();
    short* reg = &SH[0][0] + w * 4608;
    float bj[4];
    #pragma unroll
    for (int j = 0; j < 4; ++j) bj[j] = bias[c0 + wc*64 + j*16 + lm];
    #pragma unroll
    for (int i = 0; i < 4; ++i)
        #pragma unroll
        for (int j = 0; j < 4; ++j)
            #pragma unroll
            for (int r = 0; r < 4; ++r) {
                float v = acc[i][j][r] + bj[j];
                if (RELU) v = fmaxf(v, 0.f);
                reg[(i*16 + lg*4 + r)*72 + j*16 + lm] = f2bf(v);
            }
    __syncthreads();

    const int rr = l >> 3, cc = l & 7;
    float s[8] = {}, q[8] = {};
    #pragma unroll
    for (int k = 0; k < 8; ++k) {
        int rl = k * 8 + rr;
        bf16x8 vb = *(const bf16x8*)&reg[rl*72 + cc*8];
        size_t off = (size_t)(r0 + wr*64 + rl) * M + c0 + wc*64 + cc*8;
        float v[8];
        #pragma unroll
        for (int e = 0; e < 8; ++e) v[e] = bf2f(vb[e]);
        if (ADDF) {
            float4 a0 = *(const float4*)(addf + off);
            float4 a1 = *(const float4*)(addf + off + 4);
            v[0]+=a0.x; v[1]+=a0.y; v[2]+=a0.z; v[3]+=a0.w;
            v[4]+=a1.x; v[5]+=a1.y; v[6]+=a1.z; v[7]+=a1.w;
        }
        if (ADDB) {
            bf16x8 ab = *(const bf16x8*)(addb + off);
            #pragma unroll
            for (int e = 0; e < 8; ++e) v[e] += bf2f(ab[e]);
        }
        bf16x8 o;
        #pragma unroll
        for (int e = 0; e < 8; ++e) {
            if (STATS) { s[e] += v[e]; q[e] = fmaf(v[e], v[e], q[e]); }
            o[e] = f2bf(v[e]);
        }
        *(bf16x8*)(Y + off) = o;
    }
    if (STATS) {
        #pragma unroll
        for (int e = 0; e < 8; ++e) {
            #pragma unroll
            for (int m = 8; m < 64; m <<= 1) {
                s[e] += __shfl_xor(s[e], m);
                q[e] += __shfl_xor(q[e], m);
            }
        }
        if (rr == 0) {
            int col = c0 + wc*64 + cc*8;
            #pragma unroll
            for (int e = 0; e < 8; ++e) {
                atomicAdd(&st[col + e], s[e]);
                atomicAdd(&st[256 + col + e], q[e]);
            }
        }
    }
}

// ===========================================================================
// MFMA bf16 attention (bf16 QKV in, bf16 O out). Layouts verified round 3/4.
// ===========================================================================
__global__ __launch_bounds__(256) void attn_mfma(
    const short* __restrict__ QKV, short* __restrict__ O)
{
    const int bh = blockIdx.x & 255;
    const int qblk = blockIdx.x >> 8;
    const int b = bh >> 3, h = bh & 7;
    const int t = threadIdx.x, w = t >> 6, l = t & 63;
    const int lg = l >> 4, lm = l & 15;
    const size_t gb = (size_t)b * PG * 768;
    const int q0 = qblk * 128 + w * 32;
    const float rscale = 0.17677669529663687f;  // 1/sqrt(32)

    __shared__ __align__(16) short Ks[64 * 40];
    __shared__ __align__(16) short Vt[32 * 72];
    __shared__ __align__(16) short Ps[4][32 * 72];

    bf16x8 qa[2];
    #pragma unroll
    for (int qt = 0; qt < 2; ++qt)
        qa[qt] = *(const bf16x8*)(QKV + gb + (size_t)(q0 + qt*16 + lm) * 768 + h*32 + lg*8);

    f32x4 acc[2][2];
    #pragma unroll
    for (int qt = 0; qt < 2; ++qt)
        #pragma unroll
        for (int hf = 0; hf < 2; ++hf)
            acc[qt][hf] = (f32x4){0.f, 0.f, 0.f, 0.f};
    float lsum[2][4] = {};

    const int srow = t >> 2;
    const int sq = (t & 3) * 8;

    for (int kt = 0; kt < 16; ++kt) {
        bf16x8 kv = *(const bf16x8*)(QKV + gb + (size_t)(kt*64 + srow) * 768 + 256 + h*32 + sq);
        bf16x8 vv = *(const bf16x8*)(QKV + gb + (size_t)(kt*64 + srow) * 768 + 512 + h*32 + sq);
        *(bf16x8*)&Ks[srow * 40 + sq] = kv;
        #pragma unroll
        for (int j = 0; j < 8; ++j) Vt[(sq + j) * 72 + srow] = vv[j];
        __syncthreads();

        #pragma unroll
        for (int qt = 0; qt < 2; ++qt) {
            #pragma unroll
            for (int s = 0; s < 4; ++s) {
                bf16x8 kf = *(const bf16x8*)&Ks[(s*16 + lm) * 40 + lg*8];
                f32x4 c = (f32x4){0.f, 0.f, 0.f, 0.f};
                c = __builtin_amdgcn_mfma_f32_16x16x32_bf16(qa[qt], kf, c, 0, 0, 0);
                #pragma unroll
                for (int r = 0; r < 4; ++r) {
                    float p = __expf(c[r] * rscale);
                    lsum[qt][r] += p;
                    Ps[w][(qt*16 + lg*4 + r) * 72 + s*16 + lm] = f2bf(p);
                }
            }
        }

        bf16x8 vf[2][2];
        #pragma unroll
        for (int hf = 0; hf < 2; ++hf)
            #pragma unroll
            for (int g = 0; g < 2; ++g)
                vf[hf][g] = *(const bf16x8*)&Vt[(hf*16 + lm) * 72 + g*32 + lg*8];
        #pragma unroll
        for (int qt = 0; qt < 2; ++qt) {
            #pragma unroll
            for (int g = 0; g < 2; ++g) {
                bf16x8 pf = *(const bf16x8*)&Ps[w][(qt*16 + lm) * 72 + g*32 + lg*8];
                #pragma unroll
                for (int hf = 0; hf < 2; ++hf)
                    acc[qt][hf] = __builtin_amdgcn_mfma_f32_16x16x32_bf16(
                        pf, vf[hf][g], acc[qt][hf], 0, 0, 0);
            }
        }
        __syncthreads();
    }

    #pragma unroll
    for (int qt = 0; qt < 2; ++qt) {
        #pragma unroll
        for (int r = 0; r < 4; ++r) {
            float v = lsum[qt][r];
            for (int off = 1; off < 16; off <<= 1) v += __shfl_xor(v, off);
            float inv = 1.0f / v;
            int qrow = q0 + qt*16 + lg*4 + r;
            short* Op = O + ((size_t)b * PG + qrow) * D + h * 32;
            Op[lm]      = f2bf(acc[qt][0][r] * inv);
            Op[16 + lm] = f2bf(acc[qt][1][r] * inv);
        }
    }
}

// ---------------------------------------------------------------------------
// Hc = BN(A; gl,bl,st[0:512]) + BN(B; ga,ba,st[512:1024])   (bf16 in/out)
// ---------------------------------------------------------------------------
__global__ __launch_bounds__(256) void bn_combine(
    const short* __restrict__ A, const short* __restrict__ Bq,
    const float* __restrict__ gl, const float* __restrict__ bl,
    const float* __restrict__ ga, const float* __restrict__ ba,
    const float* __restrict__ st, short* __restrict__ H, int n)
{
    const float invN = 1.0f / (float)n;
    size_t i = (size_t)blockIdx.x * 256 + threadIdx.x;
    int c0 = (int)((i & 31) << 3);
    bf16x8 av = ((const bf16x8*)A)[i];
    bf16x8 bv = ((const bf16x8*)Bq)[i];
    bf16x8 o;
    #pragma unroll
    for (int e = 0; e < 8; ++e) {
        int c = c0 + e;
        float m1 = st[c] * invN;
        float v1 = fmaxf(st[256 + c] * invN - m1 * m1, 0.f);
        float m2 = st[512 + c] * invN;
        float v2 = fmaxf(st[768 + c] * invN - m2 * m2, 0.f);
        float y1 = gl[c] * (bf2f(av[e]) - m1) * rsqrtf(v1 + 1e-5f) + bl[c];
        float y2 = ga[c] * (bf2f(bv[e]) - m2) * rsqrtf(v2 + 1e-5f) + ba[c];
        o[e] = f2bf(y1 + y2);
    }
    ((bf16x8*)H)[i] = o;
}

// ---------------------------------------------------------------------------
// out(f32) = BN(X bf16; g,b,st)
// ---------------------------------------------------------------------------
__global__ __launch_bounds__(256) void bn_apply(
    const short* __restrict__ X, const float* __restrict__ g,
    const float* __restrict__ bb, const float* __restrict__ st,
    float* __restrict__ out, int n)
{
    const float invN = 1.0f / (float)n;
    size_t i = (size_t)blockIdx.x * 256 + threadIdx.x;
    int c0 = (int)((i & 31) << 3);
    bf16x8 xv = ((const bf16x8*)X)[i];
    float r[8];
    #pragma unroll
    for (int e = 0; e < 8; ++e) {
        int c = c0 + e;
        float m = st[c] * invN;
        float v = fmaxf(st[256 + c] * invN - m * m, 0.f);
        r[e] = g[c] * (bf2f(xv[e]) - m) * rsqrtf(v + 1e-5f) + bb[c];
    }
    float4 o0 = {r[0], r[1], r[2], r[3]};
    float4 o1 = {r[4], r[5], r[6], r[7]};
    ((float4*)out)[i * 2]     = o0;
    ((float4*)out)[i * 2 + 1] = o1;
}

// ---------------------------------------------------------------------------
extern "C" void kernel_launch(void* const* d_in, const int* in_sizes, int n_in,
                              void* d_out, int out_size, void* d_ws, size_t ws_size,
                              hipStream_t stream)
{
    const float* x    = (const float*)d_in[0];
    const int*   ei   = (const int*)d_in[1];
    const float* ea   = (const float*)d_in[2];
    const float* gw1  = (const float*)d_in[3];
    const float* gb1  = (const float*)d_in[4];
    const float* gw2  = (const float*)d_in[5];
    const float* gb2  = (const float*)d_in[6];
    const float* inw  = (const float*)d_in[7];
    const float* inb  = (const float*)d_in[8];
    const float* outw = (const float*)d_in[9];
    const float* outb = (const float*)d_in[10];
    const float* g1l  = (const float*)d_in[11];
    const float* b1l  = (const float*)d_in[12];
    const float* g1a  = (const float*)d_in[13];
    const float* b1a  = (const float*)d_in[14];
    const float* fw1  = (const float*)d_in[15];
    const float* fb1  = (const float*)d_in[16];
    const float* fw2  = (const float*)d_in[17];
    const float* fb2  = (const float*)d_in[18];
    const float* g2   = (const float*)d_in[19];
    const float* b2   = (const float*)d_in[20];
    float* out = (float*)d_out;

    const int N = in_sizes[0] / D;   // 32768
    const int E = in_sizes[1] / 2;   // 262144
    const size_t ND = (size_t)N * D;

    // ---- workspace: 5 bf16 N*D slots + weights + stats + CSR ----
    short* Bp = (short*)d_ws;
    short* S0 = Bp;                  // Zb -> QKV[0] -> F1b (attn-branch BN input)
    short* S1 = Bp + ND;             // T1b -> QKV[1] -> Hcb
    short* S2 = Bp + 2 * ND;         // QKV[2] -> FFHb[0]
    short* S3 = Bp + 3 * ND;         // F0b (local-branch BN input) -> FFHb[1]
    short* S4 = Bp + 4 * ND;         // Ob -> Gb (ff2 out)
    short* Wb = Bp + 5 * ND;         // 655360 shorts of bf16 weights
    short* gw1b = Wb, *gw2b = Wb + 65536, *inwb = Wb + 131072;
    short* outwb = Wb + 327680, *fw1b = Wb + 393216, *fw2b = Wb + 524288;
    float* st = (float*)(Wb + 655360);
    int* cnt    = (int*)(st + 1536);     // contiguous with st -> single memset
    int* excl   = cnt + N;
    int* rowptr = excl + N;
    int* ofs    = rowptr + N;
    int* bsum   = ofs + N;
    int* eord   = bsum + 256;
    int* esrc   = eord + E;

    const int GR = N / 128;          // 256 row-blocks
    const int EB = (E + 255) / 256;

    cvt_weights<<<320, 256, 0, stream>>>(gw1, gw2, inw, outw, fw1, fw2, Wb);

    // ---- CSR build (st + cnt zeroed in one memset) ----
    hipMemsetAsync(st, 0, (1536 + (size_t)N) * sizeof(int), stream);
    hist_kernel<<<EB, 256, 0, stream>>>(ei + E, cnt, E);
    scan_block<<<N / 256, 256, 0, stream>>>(cnt, excl, bsum);
    scan_bsum<<<1, 128, 0, stream>>>(bsum);
    scan_add<<<N / 256, 256, 0, stream>>>(excl, bsum, rowptr, ofs);
    scatter_kernel<<<EB, 256, 0, stream>>>(ei, ei + E, ofs, eord, esrc, E);

    // ---- local branch: Z -> gin1 -> gin2(+x, stats[0]) ----
    csr_aggr<<<(N * 64) / 256, 256, 0, stream>>>(x, ea, rowptr, cnt, eord, esrc, S0);
    gemm_mfma<false, true , false, false, false><<<dim3(2, GR), 256, 0, stream>>>(
        S0, nullptr, gw1b, gb1, nullptr, nullptr, S1, nullptr, 256, 256);
    gemm_mfma<false, false, true , false, true ><<<dim3(2, GR), 256, 0, stream>>>(
        S1, nullptr, gw2b, gb2, x, nullptr, S3, st, 256, 256);

    // ---- global branch: QKV(f32 x) -> attn -> outproj(+x, stats[512]) ----
    gemm_mfma<true , false, false, false, false><<<dim3(6, GR), 256, 0, stream>>>(
        nullptr, x, inwb, inb, nullptr, nullptr, S0, nullptr, 256, 768);
    attn_mfma<<<(N / PG) * 8 * 8, 256, 0, stream>>>(S0, S4);
    gemm_mfma<false, false, true , false, true ><<<dim3(2, GR), 256, 0, stream>>>(
        S4, nullptr, outwb, outb, x, nullptr, S0, st + 512, 256, 256);

    // ---- combine + FF (ff2: +Hc, stats[1024]) + final BN ----
    bn_combine<<<(unsigned)(ND / 8 / 256), 256, 0, stream>>>(
        S3, S0, g1l, b1l, g1a, b1a, st, S1, N);
    gemm_mfma<false, true , false, false, false><<<dim3(4, GR), 256, 0, stream>>>(
        S1, nullptr, fw1b, fb1, nullptr, nullptr, S2, nullptr, 256, 512);
    gemm_mfma<false, false, false, true , true ><<<dim3(2, GR), 256, 0, stream>>>(
        S2, nullptr, fw2b, fb2, nullptr, S1, S4, st + 1024, 512, 256);
    bn_apply<<<(unsigned)(ND / 8 / 256), 256, 0, stream>>>(
        S4, g2, b2, st + 1024, out, N);
}

// Round 6
// 403.713 us; speedup vs baseline: 1.6379x; 1.6379x over previous
//
#include <hip/hip_runtime.h>
#include <hip/hip_bf16.h>

constexpr int D = 256;   // dim_h
constexpr int PG = 1024; // nodes per graph

typedef __attribute__((ext_vector_type(8))) short bf16x8;  // 8 bf16 in 4 VGPRs
typedef __attribute__((ext_vector_type(4))) float f32x4;

__device__ inline short f2bf(float f) {
    __hip_bfloat16 h = __float2bfloat16(f);
    return *reinterpret_cast<short*>(&h);
}
__device__ inline float bf2f(short s) {
    return __uint_as_float(((unsigned)(unsigned short)s) << 16);
}

// ===========================================================================
// weights f32 -> bf16 (all six fused; element/8 prefixes hardcoded for D=256)
// ===========================================================================
__global__ __launch_bounds__(256) void cvt_weights(
    const float* __restrict__ w1, const float* __restrict__ w2,
    const float* __restrict__ w3, const float* __restrict__ w4,
    const float* __restrict__ w5, const float* __restrict__ w6,
    short* __restrict__ out)
{
    int i = blockIdx.x * 256 + threadIdx.x;   // [0, 81920)
    const float* src; int base;
    if (i < 16384)      { if (i < 8192) { src = w1; base = 0; }
                          else          { src = w2; base = 8192; } }
    else if (i < 40960) { src = w3; base = 16384; }
    else if (i < 49152) { src = w4; base = 40960; }
    else if (i < 65536) { src = w5; base = 49152; }
    else                { src = w6; base = 65536; }
    int k = i - base;
    float4 a = ((const float4*)src)[k * 2];
    float4 b = ((const float4*)src)[k * 2 + 1];
    bf16x8 v;
    v[0] = f2bf(a.x); v[1] = f2bf(a.y); v[2] = f2bf(a.z); v[3] = f2bf(a.w);
    v[4] = f2bf(b.x); v[5] = f2bf(b.y); v[6] = f2bf(b.z); v[7] = f2bf(b.w);
    ((bf16x8*)out)[i] = v;
}

// ===========================================================================
// CSR build: histogram -> 2-level exclusive scan -> scatter
// ===========================================================================
__global__ __launch_bounds__(256) void hist_kernel(
    const int* __restrict__ dst, int* __restrict__ cnt, int E)
{
    int e = blockIdx.x * 256 + threadIdx.x;
    if (e < E) atomicAdd(&cnt[dst[e]], 1);
}

__global__ __launch_bounds__(256) void scan_block(
    const int* __restrict__ cnt, int* __restrict__ excl, int* __restrict__ bsum)
{
    __shared__ int sm[256];
    const int t = threadIdx.x;
    const int i = blockIdx.x * 256 + t;
    int v = cnt[i];
    sm[t] = v;
    __syncthreads();
    #pragma unroll
    for (int o = 1; o < 256; o <<= 1) {
        int u = (t >= o) ? sm[t - o] : 0;
        __syncthreads();
        sm[t] += u;
        __syncthreads();
    }
    excl[i] = sm[t] - v;
    if (t == 255) bsum[blockIdx.x] = sm[255];
}

__global__ __launch_bounds__(128) void scan_bsum(int* __restrict__ bsum)
{
    __shared__ int sm[128];
    const int t = threadIdx.x;
    int v = bsum[t];
    sm[t] = v;
    __syncthreads();
    #pragma unroll
    for (int o = 1; o < 128; o <<= 1) {
        int u = (t >= o) ? sm[t - o] : 0;
        __syncthreads();
        sm[t] += u;
        __syncthreads();
    }
    bsum[t] = sm[t] - v;
}

__global__ __launch_bounds__(256) void scan_add(
    const int* __restrict__ excl, const int* __restrict__ bsum,
    int* __restrict__ rowptr, int* __restrict__ ofs)
{
    int i = blockIdx.x * 256 + threadIdx.x;
    int r = excl[i] + bsum[blockIdx.x];
    rowptr[i] = r;
    ofs[i] = r;
}

__global__ __launch_bounds__(256) void scatter_kernel(
    const int* __restrict__ src, const int* __restrict__ dst,
    int* __restrict__ ofs, int* __restrict__ eord, int* __restrict__ esrc, int E)
{
    int e = blockIdx.x * 256 + threadIdx.x;
    if (e >= E) return;
    int d = dst[e];
    int pos = atomicAdd(&ofs[d], 1);
    eord[pos] = e;
    esrc[pos] = src[e];
}

// ===========================================================================
// CSR aggregation -> bf16 Z. One wave per dst node.
// ===========================================================================
__global__ __launch_bounds__(256) void csr_aggr(
    const float* __restrict__ x, const float* __restrict__ ea,
    const int* __restrict__ rowptr, const int* __restrict__ cnt,
    const int* __restrict__ eord, const int* __restrict__ esrc,
    short* __restrict__ z)
{
    int gid = blockIdx.x * 256 + threadIdx.x;
    int node = gid >> 6;
    int c = (gid & 63) << 2;
    int start = rowptr[node];
    int deg = cnt[node];
    float4 acc = *(const float4*)(x + (size_t)node * D + c);
    for (int i = 0; i < deg; ++i) {
        int e = eord[start + i];
        int s = esrc[start + i];
        float4 xa = *(const float4*)(x + (size_t)s * D + c);
        float4 av = *(const float4*)(ea + (size_t)e * D + c);
        acc.x += fmaxf(xa.x + av.x, 0.f);
        acc.y += fmaxf(xa.y + av.y, 0.f);
        acc.z += fmaxf(xa.z + av.z, 0.f);
        acc.w += fmaxf(xa.w + av.w, 0.f);
    }
    short4 r;
    r.x = f2bf(acc.x); r.y = f2bf(acc.y); r.z = f2bf(acc.z); r.w = f2bf(acc.w);
    *(short4*)(z + (size_t)node * D + c) = r;
}

// ===========================================================================
// MFMA bf16 GEMM: Y(bf16) = relu?(X @ W^T + bias) (+ addf/addb), fused BN stats.
// Tile 128x128, BK=64, 4 waves. Round-4 direct-store epilogue (proven fast);
// stats accumulated inline in 8 VGPRs, shfl-reduced over lg, 8 atomics/thread-grp.
// ===========================================================================
template<bool XF32, bool RELU, bool ADDF, bool ADDB, bool STATS>
__global__ __launch_bounds__(256) void gemm_mfma(
    const short* __restrict__ X, const float* __restrict__ Xf,
    const short* __restrict__ W, const float* __restrict__ bias,
    const float* __restrict__ addf, const short* __restrict__ addb,
    short* __restrict__ Y, float* __restrict__ st, int K, int M)
{
    __shared__ __align__(16) short Xs[128 * 72];
    __shared__ __align__(16) short Ws[128 * 72];

    const int nbx = gridDim.x;
    const int nwg = nbx * gridDim.y;
    const int bid = blockIdx.y * nbx + blockIdx.x;
    const int cpx = nwg >> 3;                     // all grids are %8 == 0
    const int wg  = (bid & 7) * cpx + (bid >> 3);
    const int r0 = (wg / nbx) * 128;
    const int c0 = (wg % nbx) * 128;

    const int t = threadIdx.x, w = t >> 6, l = t & 63;
    const int wr = w >> 1, wc = w & 1, lg = l >> 4, lm = l & 15;
    const int srow = t >> 3;            // staging row 0..31
    const int scol = (t & 7) * 8;       // staging col 0..56

    f32x4 acc[4][4];
    #pragma unroll
    for (int i = 0; i < 4; ++i)
        #pragma unroll
        for (int j = 0; j < 4; ++j)
            acc[i][j] = (f32x4){0.f, 0.f, 0.f, 0.f};

    for (int k0 = 0; k0 < K; k0 += 64) {
        __syncthreads();
        #pragma unroll
        for (int it = 0; it < 4; ++it) {
            int r = it * 32 + srow;
            bf16x8 xv;
            if (XF32) {
                const float* p = Xf + (size_t)(r0 + r) * K + k0 + scol;
                float4 a = *(const float4*)p;
                float4 b = *(const float4*)(p + 4);
                xv[0] = f2bf(a.x); xv[1] = f2bf(a.y); xv[2] = f2bf(a.z); xv[3] = f2bf(a.w);
                xv[4] = f2bf(b.x); xv[5] = f2bf(b.y); xv[6] = f2bf(b.z); xv[7] = f2bf(b.w);
            } else {
                xv = *(const bf16x8*)(X + (size_t)(r0 + r) * K + k0 + scol);
            }
            bf16x8 wv = *(const bf16x8*)(W + (size_t)(c0 + r) * K + k0 + scol);
            *(bf16x8*)&Xs[r * 72 + scol] = xv;
            *(bf16x8*)&Ws[r * 72 + scol] = wv;
        }
        __syncthreads();

        bf16x8 af[4][2], bfr[4][2];
        #pragma unroll
        for (int i = 0; i < 4; ++i)
            #pragma unroll
            for (int ks = 0; ks < 2; ++ks) {
                af[i][ks]  = *(const bf16x8*)&Xs[(wr*64 + i*16 + lm)*72 + ks*32 + lg*8];
                bfr[i][ks] = *(const bf16x8*)&Ws[(wc*64 + i*16 + lm)*72 + ks*32 + lg*8];
            }
        #pragma unroll
        for (int i = 0; i < 4; ++i)
            #pragma unroll
            for (int j = 0; j < 4; ++j) {
                acc[i][j] = __builtin_amdgcn_mfma_f32_16x16x32_bf16(af[i][0], bfr[j][0], acc[i][j], 0, 0, 0);
                acc[i][j] = __builtin_amdgcn_mfma_f32_16x16x32_bf16(af[i][1], bfr[j][1], acc[i][j], 0, 0, 0);
            }
    }

    // ---- epilogue: round-4 direct stores + inline stats ----
    float s4[4] = {}, q4[4] = {};
    #pragma unroll
    for (int j = 0; j < 4; ++j) {
        int col = c0 + wc*64 + j*16 + lm;
        float bj = bias[col];
        #pragma unroll
        for (int i = 0; i < 4; ++i) {
            #pragma unroll
            for (int r = 0; r < 4; ++r) {
                int row = r0 + wr*64 + i*16 + lg*4 + r;
                size_t off = (size_t)row * M + col;
                float v = acc[i][j][r] + bj;
                if (RELU) v = fmaxf(v, 0.f);
                if (ADDF) v += addf[off];
                if (ADDB) v += bf2f(addb[off]);
                if (STATS) { s4[j] += v; q4[j] = fmaf(v, v, q4[j]); }
                Y[off] = f2bf(v);
            }
        }
    }
    if (STATS) {
        #pragma unroll
        for (int j = 0; j < 4; ++j) {
            s4[j] += __shfl_xor(s4[j], 16); q4[j] += __shfl_xor(q4[j], 16);
            s4[j] += __shfl_xor(s4[j], 32); q4[j] += __shfl_xor(q4[j], 32);
        }
        if (lg == 0) {
            #pragma unroll
            for (int j = 0; j < 4; ++j) {
                int col = c0 + wc*64 + j*16 + lm;
                atomicAdd(&st[col], s4[j]);
                atomicAdd(&st[256 + col], q4[j]);
            }
        }
    }
}

// ===========================================================================
// MFMA bf16 attention (bf16 QKV in, bf16 O out). Layouts verified round 3/4.
// ===========================================================================
__global__ __launch_bounds__(256) void attn_mfma(
    const short* __restrict__ QKV, short* __restrict__ O)
{
    const int bh = blockIdx.x & 255;
    const int qblk = blockIdx.x >> 8;
    const int b = bh >> 3, h = bh & 7;
    const int t = threadIdx.x, w = t >> 6, l = t & 63;
    const int lg = l >> 4, lm = l & 15;
    const size_t gb = (size_t)b * PG * 768;
    const int q0 = qblk * 128 + w * 32;
    const float rscale = 0.17677669529663687f;  // 1/sqrt(32)

    __shared__ __align__(16) short Ks[64 * 40];
    __shared__ __align__(16) short Vt[32 * 72];
    __shared__ __align__(16) short Ps[4][32 * 72];

    bf16x8 qa[2];
    #pragma unroll
    for (int qt = 0; qt < 2; ++qt)
        qa[qt] = *(const bf16x8*)(QKV + gb + (size_t)(q0 + qt*16 + lm) * 768 + h*32 + lg*8);

    f32x4 acc[2][2];
    #pragma unroll
    for (int qt = 0; qt < 2; ++qt)
        #pragma unroll
        for (int hf = 0; hf < 2; ++hf)
            acc[qt][hf] = (f32x4){0.f, 0.f, 0.f, 0.f};
    float lsum[2][4] = {};

    const int srow = t >> 2;
    const int sq = (t & 3) * 8;

    for (int kt = 0; kt < 16; ++kt) {
        bf16x8 kv = *(const bf16x8*)(QKV + gb + (size_t)(kt*64 + srow) * 768 + 256 + h*32 + sq);
        bf16x8 vv = *(const bf16x8*)(QKV + gb + (size_t)(kt*64 + srow) * 768 + 512 + h*32 + sq);
        *(bf16x8*)&Ks[srow * 40 + sq] = kv;
        #pragma unroll
        for (int j = 0; j < 8; ++j) Vt[(sq + j) * 72 + srow] = vv[j];
        __syncthreads();

        #pragma unroll
        for (int qt = 0; qt < 2; ++qt) {
            #pragma unroll
            for (int s = 0; s < 4; ++s) {
                bf16x8 kf = *(const bf16x8*)&Ks[(s*16 + lm) * 40 + lg*8];
                f32x4 c = (f32x4){0.f, 0.f, 0.f, 0.f};
                c = __builtin_amdgcn_mfma_f32_16x16x32_bf16(qa[qt], kf, c, 0, 0, 0);
                #pragma unroll
                for (int r = 0; r < 4; ++r) {
                    float p = __expf(c[r] * rscale);
                    lsum[qt][r] += p;
                    Ps[w][(qt*16 + lg*4 + r) * 72 + s*16 + lm] = f2bf(p);
                }
            }
        }

        bf16x8 vf[2][2];
        #pragma unroll
        for (int hf = 0; hf < 2; ++hf)
            #pragma unroll
            for (int g = 0; g < 2; ++g)
                vf[hf][g] = *(const bf16x8*)&Vt[(hf*16 + lm) * 72 + g*32 + lg*8];
        #pragma unroll
        for (int qt = 0; qt < 2; ++qt) {
            #pragma unroll
            for (int g = 0; g < 2; ++g) {
                bf16x8 pf = *(const bf16x8*)&Ps[w][(qt*16 + lm) * 72 + g*32 + lg*8];
                #pragma unroll
                for (int hf = 0; hf < 2; ++hf)
                    acc[qt][hf] = __builtin_amdgcn_mfma_f32_16x16x32_bf16(
                        pf, vf[hf][g], acc[qt][hf], 0, 0, 0);
            }
        }
        __syncthreads();
    }

    #pragma unroll
    for (int qt = 0; qt < 2; ++qt) {
        #pragma unroll
        for (int r = 0; r < 4; ++r) {
            float v = lsum[qt][r];
            for (int off = 1; off < 16; off <<= 1) v += __shfl_xor(v, off);
            float inv = 1.0f / v;
            int qrow = q0 + qt*16 + lg*4 + r;
            short* Op = O + ((size_t)b * PG + qrow) * D + h * 32;
            Op[lm]      = f2bf(acc[qt][0][r] * inv);
            Op[16 + lm] = f2bf(acc[qt][1][r] * inv);
        }
    }
}

// ---------------------------------------------------------------------------
// Hc = BN(A; gl,bl,st[0:512]) + BN(B; ga,ba,st[512:1024])   (bf16 in/out)
// ---------------------------------------------------------------------------
__global__ __launch_bounds__(256) void bn_combine(
    const short* __restrict__ A, const short* __restrict__ Bq,
    const float* __restrict__ gl, const float* __restrict__ bl,
    const float* __restrict__ ga, const float* __restrict__ ba,
    const float* __restrict__ st, short* __restrict__ H, int n)
{
    const float invN = 1.0f / (float)n;
    size_t i = (size_t)blockIdx.x * 256 + threadIdx.x;
    int c0 = (int)((i & 31) << 3);
    bf16x8 av = ((const bf16x8*)A)[i];
    bf16x8 bv = ((const bf16x8*)Bq)[i];
    bf16x8 o;
    #pragma unroll
    for (int e = 0; e < 8; ++e) {
        int c = c0 + e;
        float m1 = st[c] * invN;
        float v1 = fmaxf(st[256 + c] * invN - m1 * m1, 0.f);
        float m2 = st[512 + c] * invN;
        float v2 = fmaxf(st[768 + c] * invN - m2 * m2, 0.f);
        float y1 = gl[c] * (bf2f(av[e]) - m1) * rsqrtf(v1 + 1e-5f) + bl[c];
        float y2 = ga[c] * (bf2f(bv[e]) - m2) * rsqrtf(v2 + 1e-5f) + ba[c];
        o[e] = f2bf(y1 + y2);
    }
    ((bf16x8*)H)[i] = o;
}

// ---------------------------------------------------------------------------
// out(f32) = BN(X bf16; g,b,st)
// ---------------------------------------------------------------------------
__global__ __launch_bounds__(256) void bn_apply(
    const short* __restrict__ X, const float* __restrict__ g,
    const float* __restrict__ bb, const float* __restrict__ st,
    float* __restrict__ out, int n)
{
    const float invN = 1.0f / (float)n;
    size_t i = (size_t)blockIdx.x * 256 + threadIdx.x;
    int c0 = (int)((i & 31) << 3);
    bf16x8 xv = ((const bf16x8*)X)[i];
    float r[8];
    #pragma unroll
    for (int e = 0; e < 8; ++e) {
        int c = c0 + e;
        float m = st[c] * invN;
        float v = fmaxf(st[256 + c] * invN - m * m, 0.f);
        r[e] = g[c] * (bf2f(xv[e]) - m) * rsqrtf(v + 1e-5f) + bb[c];
    }
    float4 o0 = {r[0], r[1], r[2], r[3]};
    float4 o1 = {r[4], r[5], r[6], r[7]};
    ((float4*)out)[i * 2]     = o0;
    ((float4*)out)[i * 2 + 1] = o1;
}

// ---------------------------------------------------------------------------
extern "C" void kernel_launch(void* const* d_in, const int* in_sizes, int n_in,
                              void* d_out, int out_size, void* d_ws, size_t ws_size,
                              hipStream_t stream)
{
    const float* x    = (const float*)d_in[0];
    const int*   ei   = (const int*)d_in[1];
    const float* ea   = (const float*)d_in[2];
    const float* gw1  = (const float*)d_in[3];
    const float* gb1  = (const float*)d_in[4];
    const float* gw2  = (const float*)d_in[5];
    const float* gb2  = (const float*)d_in[6];
    const float* inw  = (const float*)d_in[7];
    const float* inb  = (const float*)d_in[8];
    const float* outw = (const float*)d_in[9];
    const float* outb = (const float*)d_in[10];
    const float* g1l  = (const float*)d_in[11];
    const float* b1l  = (const float*)d_in[12];
    const float* g1a  = (const float*)d_in[13];
    const float* b1a  = (const float*)d_in[14];
    const float* fw1  = (const float*)d_in[15];
    const float* fb1  = (const float*)d_in[16];
    const float* fw2  = (const float*)d_in[17];
    const float* fb2  = (const float*)d_in[18];
    const float* g2   = (const float*)d_in[19];
    const float* b2   = (const float*)d_in[20];
    float* out = (float*)d_out;

    const int N = in_sizes[0] / D;   // 32768
    const int E = in_sizes[1] / 2;   // 262144
    const size_t ND = (size_t)N * D;

    // ---- workspace: 5 bf16 N*D slots + weights + stats + CSR ----
    short* Bp = (short*)d_ws;
    short* S0 = Bp;                  // Zb -> QKV[0] -> F1b (attn-branch BN input)
    short* S1 = Bp + ND;             // T1b -> QKV[1] -> Hcb
    short* S2 = Bp + 2 * ND;         // QKV[2] -> FFHb[0]
    short* S3 = Bp + 3 * ND;         // F0b (local-branch BN input) -> FFHb[1]
    short* S4 = Bp + 4 * ND;         // Ob -> Gb (ff2 out)
    short* Wb = Bp + 5 * ND;         // 655360 shorts of bf16 weights
    short* gw1b = Wb, *gw2b = Wb + 65536, *inwb = Wb + 131072;
    short* outwb = Wb + 327680, *fw1b = Wb + 393216, *fw2b = Wb + 524288;
    float* st = (float*)(Wb + 655360);
    int* cnt    = (int*)(st + 1536);     // contiguous with st -> single memset
    int* excl   = cnt + N;
    int* rowptr = excl + N;
    int* ofs    = rowptr + N;
    int* bsum   = ofs + N;
    int* eord   = bsum + 256;
    int* esrc   = eord + E;

    const int GR = N / 128;          // 256 row-blocks
    const int EB = (E + 255) / 256;

    cvt_weights<<<320, 256, 0, stream>>>(gw1, gw2, inw, outw, fw1, fw2, Wb);

    // ---- CSR build (st + cnt zeroed in one memset) ----
    hipMemsetAsync(st, 0, (1536 + (size_t)N) * sizeof(int), stream);
    hist_kernel<<<EB, 256, 0, stream>>>(ei + E, cnt, E);
    scan_block<<<N / 256, 256, 0, stream>>>(cnt, excl, bsum);
    scan_bsum<<<1, 128, 0, stream>>>(bsum);
    scan_add<<<N / 256, 256, 0, stream>>>(excl, bsum, rowptr, ofs);
    scatter_kernel<<<EB, 256, 0, stream>>>(ei, ei + E, ofs, eord, esrc, E);

    // ---- local branch: Z -> gin1 -> gin2(+x, stats[0]) ----
    csr_aggr<<<(N * 64) / 256, 256, 0, stream>>>(x, ea, rowptr, cnt, eord, esrc, S0);
    gemm_mfma<false, true , false, false, false><<<dim3(2, GR), 256, 0, stream>>>(
        S0, nullptr, gw1b, gb1, nullptr, nullptr, S1, nullptr, 256, 256);
    gemm_mfma<false, false, true , false, true ><<<dim3(2, GR), 256, 0, stream>>>(
        S1, nullptr, gw2b, gb2, x, nullptr, S3, st, 256, 256);

    // ---- global branch: QKV(f32 x) -> attn -> outproj(+x, stats[512]) ----
    gemm_mfma<true , false, false, false, false><<<dim3(6, GR), 256, 0, stream>>>(
        nullptr, x, inwb, inb, nullptr, nullptr, S0, nullptr, 256, 768);
    attn_mfma<<<(N / PG) * 8 * 8, 256, 0, stream>>>(S0, S4);
    gemm_mfma<false, false, true , false, true ><<<dim3(2, GR), 256, 0, stream>>>(
        S4, nullptr, outwb, outb, x, nullptr, S0, st + 512, 256, 256);

    // ---- combine + FF (ff2: +Hc, stats[1024]) + final BN ----
    bn_combine<<<(unsigned)(ND / 8 / 256), 256, 0, stream>>>(
        S3, S0, g1l, b1l, g1a, b1a, st, S1, N);
    gemm_mfma<false, true , false, false, false><<<dim3(4, GR), 256, 0, stream>>>(
        S1, nullptr, fw1b, fb1, nullptr, nullptr, S2, nullptr, 256, 512);
    gemm_mfma<false, false, false, true , true ><<<dim3(2, GR), 256, 0, stream>>>(
        S2, nullptr, fw2b, fb2, nullptr, S1, S4, st + 1024, 512, 256);
    bn_apply<<<(unsigned)(ND / 8 / 256), 256, 0, stream>>>(
        S4, g2, b2, st + 1024, out, N);
}

// Round 7
// 390.327 us; speedup vs baseline: 1.6940x; 1.0343x over previous
//
#include <hip/hip_runtime.h>
#include <hip/hip_bf16.h>

constexpr int D = 256;   // dim_h
constexpr int PG = 1024; // nodes per graph

typedef __attribute__((ext_vector_type(8))) short bf16x8;  // 8 bf16 in 4 VGPRs
typedef __attribute__((ext_vector_type(4))) float f32x4;

__device__ inline short f2bf(float f) {
    __hip_bfloat16 h = __float2bfloat16(f);
    return *reinterpret_cast<short*>(&h);
}
__device__ inline float bf2f(short s) {
    return __uint_as_float(((unsigned)(unsigned short)s) << 16);
}

// ===========================================================================
// weights f32 -> bf16 (all six fused; element/8 prefixes hardcoded for D=256)
// ===========================================================================
__global__ __launch_bounds__(256) void cvt_weights(
    const float* __restrict__ w1, const float* __restrict__ w2,
    const float* __restrict__ w3, const float* __restrict__ w4,
    const float* __restrict__ w5, const float* __restrict__ w6,
    short* __restrict__ out)
{
    int i = blockIdx.x * 256 + threadIdx.x;   // [0, 81920)
    const float* src; int base;
    if (i < 16384)      { if (i < 8192) { src = w1; base = 0; }
                          else          { src = w2; base = 8192; } }
    else if (i < 40960) { src = w3; base = 16384; }
    else if (i < 49152) { src = w4; base = 40960; }
    else if (i < 65536) { src = w5; base = 49152; }
    else                { src = w6; base = 65536; }
    int k = i - base;
    float4 a = ((const float4*)src)[k * 2];
    float4 b = ((const float4*)src)[k * 2 + 1];
    bf16x8 v;
    v[0] = f2bf(a.x); v[1] = f2bf(a.y); v[2] = f2bf(a.z); v[3] = f2bf(a.w);
    v[4] = f2bf(b.x); v[5] = f2bf(b.y); v[6] = f2bf(b.z); v[7] = f2bf(b.w);
    ((bf16x8*)out)[i] = v;
}

// ===========================================================================
// CSR build: histogram -> 2-level exclusive scan -> scatter
// ===========================================================================
__global__ __launch_bounds__(256) void hist_kernel(
    const int* __restrict__ dst, int* __restrict__ cnt, int E)
{
    int e = blockIdx.x * 256 + threadIdx.x;
    if (e < E) atomicAdd(&cnt[dst[e]], 1);
}

__global__ __launch_bounds__(256) void scan_block(
    const int* __restrict__ cnt, int* __restrict__ excl, int* __restrict__ bsum)
{
    __shared__ int sm[256];
    const int t = threadIdx.x;
    const int i = blockIdx.x * 256 + t;
    int v = cnt[i];
    sm[t] = v;
    __syncthreads();
    #pragma unroll
    for (int o = 1; o < 256; o <<= 1) {
        int u = (t >= o) ? sm[t - o] : 0;
        __syncthreads();
        sm[t] += u;
        __syncthreads();
    }
    excl[i] = sm[t] - v;
    if (t == 255) bsum[blockIdx.x] = sm[255];
}

__global__ __launch_bounds__(128) void scan_bsum(int* __restrict__ bsum)
{
    __shared__ int sm[128];
    const int t = threadIdx.x;
    int v = bsum[t];
    sm[t] = v;
    __syncthreads();
    #pragma unroll
    for (int o = 1; o < 128; o <<= 1) {
        int u = (t >= o) ? sm[t - o] : 0;
        __syncthreads();
        sm[t] += u;
        __syncthreads();
    }
    bsum[t] = sm[t] - v;
}

__global__ __launch_bounds__(256) void scan_add(
    const int* __restrict__ excl, const int* __restrict__ bsum,
    int* __restrict__ rowptr, int* __restrict__ ofs)
{
    int i = blockIdx.x * 256 + threadIdx.x;
    int r = excl[i] + bsum[blockIdx.x];
    rowptr[i] = r;
    ofs[i] = r;
}

__global__ __launch_bounds__(256) void scatter_kernel(
    const int* __restrict__ src, const int* __restrict__ dst,
    int* __restrict__ ofs, int* __restrict__ eord, int* __restrict__ esrc, int E)
{
    int e = blockIdx.x * 256 + threadIdx.x;
    if (e >= E) return;
    int d = dst[e];
    int pos = atomicAdd(&ofs[d], 1);
    eord[pos] = e;
    esrc[pos] = src[e];
}

// ===========================================================================
// CSR aggregation -> bf16 Z. One wave per dst node.
// ===========================================================================
__global__ __launch_bounds__(256) void csr_aggr(
    const float* __restrict__ x, const float* __restrict__ ea,
    const int* __restrict__ rowptr, const int* __restrict__ cnt,
    const int* __restrict__ eord, const int* __restrict__ esrc,
    short* __restrict__ z)
{
    int gid = blockIdx.x * 256 + threadIdx.x;
    int node = gid >> 6;
    int c = (gid & 63) << 2;
    int start = rowptr[node];
    int deg = cnt[node];
    float4 acc = *(const float4*)(x + (size_t)node * D + c);
    for (int i = 0; i < deg; ++i) {
        int e = eord[start + i];
        int s = esrc[start + i];
        float4 xa = *(const float4*)(x + (size_t)s * D + c);
        float4 av = *(const float4*)(ea + (size_t)e * D + c);
        acc.x += fmaxf(xa.x + av.x, 0.f);
        acc.y += fmaxf(xa.y + av.y, 0.f);
        acc.z += fmaxf(xa.z + av.z, 0.f);
        acc.w += fmaxf(xa.w + av.w, 0.f);
    }
    short4 r;
    r.x = f2bf(acc.x); r.y = f2bf(acc.y); r.z = f2bf(acc.z); r.w = f2bf(acc.w);
    *(short4*)(z + (size_t)node * D + c) = r;
}

// ===========================================================================
// MFMA bf16 GEMM: Y(bf16) = relu?(X @ W^T + bias)(*rscale for Q cols)(+ addf/b),
// fused BN stats. Tile 128x128, BK=64, 4 waves. Direct-store epilogue.
// ===========================================================================
template<bool XF32, bool RELU, bool ADDF, bool ADDB, bool STATS, bool SCALEQ>
__global__ __launch_bounds__(256) void gemm_mfma(
    const short* __restrict__ X, const float* __restrict__ Xf,
    const short* __restrict__ W, const float* __restrict__ bias,
    const float* __restrict__ addf, const short* __restrict__ addb,
    short* __restrict__ Y, float* __restrict__ st, int K, int M)
{
    __shared__ __align__(16) short Xs[128 * 72];
    __shared__ __align__(16) short Ws[128 * 72];

    const int nbx = gridDim.x;
    const int nwg = nbx * gridDim.y;
    const int bid = blockIdx.y * nbx + blockIdx.x;
    const int cpx = nwg >> 3;                     // all grids are %8 == 0
    const int wg  = (bid & 7) * cpx + (bid >> 3);
    const int r0 = (wg / nbx) * 128;
    const int c0 = (wg % nbx) * 128;

    const int t = threadIdx.x, w = t >> 6, l = t & 63;
    const int wr = w >> 1, wc = w & 1, lg = l >> 4, lm = l & 15;
    const int srow = t >> 3;            // staging row 0..31
    const int scol = (t & 7) * 8;       // staging col 0..56

    f32x4 acc[4][4];
    #pragma unroll
    for (int i = 0; i < 4; ++i)
        #pragma unroll
        for (int j = 0; j < 4; ++j)
            acc[i][j] = (f32x4){0.f, 0.f, 0.f, 0.f};

    for (int k0 = 0; k0 < K; k0 += 64) {
        __syncthreads();
        #pragma unroll
        for (int it = 0; it < 4; ++it) {
            int r = it * 32 + srow;
            bf16x8 xv;
            if (XF32) {
                const float* p = Xf + (size_t)(r0 + r) * K + k0 + scol;
                float4 a = *(const float4*)p;
                float4 b = *(const float4*)(p + 4);
                xv[0] = f2bf(a.x); xv[1] = f2bf(a.y); xv[2] = f2bf(a.z); xv[3] = f2bf(a.w);
                xv[4] = f2bf(b.x); xv[5] = f2bf(b.y); xv[6] = f2bf(b.z); xv[7] = f2bf(b.w);
            } else {
                xv = *(const bf16x8*)(X + (size_t)(r0 + r) * K + k0 + scol);
            }
            bf16x8 wv = *(const bf16x8*)(W + (size_t)(c0 + r) * K + k0 + scol);
            *(bf16x8*)&Xs[r * 72 + scol] = xv;
            *(bf16x8*)&Ws[r * 72 + scol] = wv;
        }
        __syncthreads();

        bf16x8 af[4][2], bfr[4][2];
        #pragma unroll
        for (int i = 0; i < 4; ++i)
            #pragma unroll
            for (int ks = 0; ks < 2; ++ks) {
                af[i][ks]  = *(const bf16x8*)&Xs[(wr*64 + i*16 + lm)*72 + ks*32 + lg*8];
                bfr[i][ks] = *(const bf16x8*)&Ws[(wc*64 + i*16 + lm)*72 + ks*32 + lg*8];
            }
        #pragma unroll
        for (int i = 0; i < 4; ++i)
            #pragma unroll
            for (int j = 0; j < 4; ++j) {
                acc[i][j] = __builtin_amdgcn_mfma_f32_16x16x32_bf16(af[i][0], bfr[j][0], acc[i][j], 0, 0, 0);
                acc[i][j] = __builtin_amdgcn_mfma_f32_16x16x32_bf16(af[i][1], bfr[j][1], acc[i][j], 0, 0, 0);
            }
    }

    // ---- epilogue: direct stores + inline stats ----
    float s4[4] = {}, q4[4] = {};
    #pragma unroll
    for (int j = 0; j < 4; ++j) {
        int col = c0 + wc*64 + j*16 + lm;
        float bj = bias[col];
        #pragma unroll
        for (int i = 0; i < 4; ++i) {
            #pragma unroll
            for (int r = 0; r < 4; ++r) {
                int row = r0 + wr*64 + i*16 + lg*4 + r;
                size_t off = (size_t)row * M + col;
                float v = acc[i][j][r] + bj;
                if (RELU) v = fmaxf(v, 0.f);
                if (SCALEQ) { if (col < 256) v *= 0.17677669529663687f; }
                if (ADDF) v += addf[off];
                if (ADDB) v += bf2f(addb[off]);
                if (STATS) { s4[j] += v; q4[j] = fmaf(v, v, q4[j]); }
                Y[off] = f2bf(v);
            }
        }
    }
    if (STATS) {
        #pragma unroll
        for (int j = 0; j < 4; ++j) {
            s4[j] += __shfl_xor(s4[j], 16); q4[j] += __shfl_xor(q4[j], 16);
            s4[j] += __shfl_xor(s4[j], 32); q4[j] += __shfl_xor(q4[j], 32);
        }
        if (lg == 0) {
            #pragma unroll
            for (int j = 0; j < 4; ++j) {
                int col = c0 + wc*64 + j*16 + lm;
                atomicAdd(&st[col], s4[j]);
                atomicAdd(&st[256 + col], q4[j]);
            }
        }
    }
}

// ===========================================================================
// MFMA bf16 attention. Swapped QK^T: S = mfma(K,Q) -> lane holds 4 consecutive
// k for one q-row -> P writes pack to ds_write_b64; denom is lane-local.
// Q pre-scaled by 1/sqrt(dh) in the QKV GEMM. K/V staged with reg prefetch.
// ===========================================================================
__global__ __launch_bounds__(256) void attn_mfma(
    const short* __restrict__ QKV, short* __restrict__ O)
{
    const int bh = blockIdx.x & 255;
    const int qblk = blockIdx.x >> 8;
    const int b = bh >> 3, h = bh & 7;
    const int t = threadIdx.x, w = t >> 6, l = t & 63;
    const int lg = l >> 4, lm = l & 15;
    const size_t gb = (size_t)b * PG * 768;
    const int q0 = qblk * 128 + w * 32;

    __shared__ __align__(16) short Ks[64 * 40];
    __shared__ __align__(16) short Vt[32 * 72];
    __shared__ __align__(16) short Ps[4][32 * 72];

    bf16x8 qa[2];
    #pragma unroll
    for (int qt = 0; qt < 2; ++qt)
        qa[qt] = *(const bf16x8*)(QKV + gb + (size_t)(q0 + qt*16 + lm) * 768 + h*32 + lg*8);

    f32x4 acc[2][2];
    #pragma unroll
    for (int qt = 0; qt < 2; ++qt)
        #pragma unroll
        for (int hf = 0; hf < 2; ++hf)
            acc[qt][hf] = (f32x4){0.f, 0.f, 0.f, 0.f};
    float lsum[2] = {0.f, 0.f};

    const int srow = t >> 2;
    const int sq = (t & 3) * 8;
    const short* Kb = QKV + gb + 256 + h*32 + sq;
    const short* Vb = QKV + gb + 512 + h*32 + sq;

    bf16x8 kreg = *(const bf16x8*)(Kb + (size_t)srow * 768);
    bf16x8 vreg = *(const bf16x8*)(Vb + (size_t)srow * 768);

    for (int kt = 0; kt < 16; ++kt) {
        // ---- write staged tile, then prefetch next into regs ----
        *(bf16x8*)&Ks[srow * 40 + sq] = kreg;
        #pragma unroll
        for (int j = 0; j < 8; ++j) Vt[(sq + j) * 72 + srow] = vreg[j];
        __syncthreads();
        if (kt < 15) {
            kreg = *(const bf16x8*)(Kb + (size_t)((kt + 1) * 64 + srow) * 768);
            vreg = *(const bf16x8*)(Vb + (size_t)((kt + 1) * 64 + srow) * 768);
        }

        // ---- QK^T (swapped) + exp + packed P -> LDS ----
        bf16x8 kf[4];
        #pragma unroll
        for (int s = 0; s < 4; ++s)
            kf[s] = *(const bf16x8*)&Ks[(s*16 + lm) * 40 + lg*8];

        #pragma unroll
        for (int qt = 0; qt < 2; ++qt) {
            #pragma unroll
            for (int s = 0; s < 4; ++s) {
                f32x4 c = (f32x4){0.f, 0.f, 0.f, 0.f};
                c = __builtin_amdgcn_mfma_f32_16x16x32_bf16(kf[s], qa[qt], c, 0, 0, 0);
                float p0 = __expf(c[0]), p1 = __expf(c[1]);
                float p2 = __expf(c[2]), p3 = __expf(c[3]);
                lsum[qt] += (p0 + p1) + (p2 + p3);
                short4 pk;
                pk.x = f2bf(p0); pk.y = f2bf(p1); pk.z = f2bf(p2); pk.w = f2bf(p3);
                *(short4*)&Ps[w][(qt*16 + lm) * 72 + s*16 + lg*4] = pk;
            }
        }

        // ---- PV ----
        bf16x8 vf[2][2];
        #pragma unroll
        for (int hf = 0; hf < 2; ++hf)
            #pragma unroll
            for (int g = 0; g < 2; ++g)
                vf[hf][g] = *(const bf16x8*)&Vt[(hf*16 + lm) * 72 + g*32 + lg*8];
        #pragma unroll
        for (int qt = 0; qt < 2; ++qt) {
            #pragma unroll
            for (int g = 0; g < 2; ++g) {
                bf16x8 pf = *(const bf16x8*)&Ps[w][(qt*16 + lm) * 72 + g*32 + lg*8];
                #pragma unroll
                for (int hf = 0; hf < 2; ++hf)
                    acc[qt][hf] = __builtin_amdgcn_mfma_f32_16x16x32_bf16(
                        pf, vf[hf][g], acc[qt][hf], 0, 0, 0);
            }
        }
        __syncthreads();
    }

    // ---- denominator: lane-local sum -> reduce over lg -> broadcast ----
    float red[2];
    #pragma unroll
    for (int qt = 0; qt < 2; ++qt) {
        float v = lsum[qt];
        v += __shfl_xor(v, 16);
        v += __shfl_xor(v, 32);
        red[qt] = 1.0f / v;         // valid for q = qt*16 + lm
    }
    #pragma unroll
    for (int qt = 0; qt < 2; ++qt) {
        #pragma unroll
        for (int r = 0; r < 4; ++r) {
            float inv = __shfl(red[qt], lg*4 + r);
            int qrow = q0 + qt*16 + lg*4 + r;
            short* Op = O + ((size_t)b * PG + qrow) * D + h * 32;
            Op[lm]      = f2bf(acc[qt][0][r] * inv);
            Op[16 + lm] = f2bf(acc[qt][1][r] * inv);
        }
    }
}

// ---------------------------------------------------------------------------
// Hc = BN(A; gl,bl,st[0:512]) + BN(B; ga,ba,st[512:1024])   (bf16 in/out)
// ---------------------------------------------------------------------------
__global__ __launch_bounds__(256) void bn_combine(
    const short* __restrict__ A, const short* __restrict__ Bq,
    const float* __restrict__ gl, const float* __restrict__ bl,
    const float* __restrict__ ga, const float* __restrict__ ba,
    const float* __restrict__ st, short* __restrict__ H, int n)
{
    const float invN = 1.0f / (float)n;
    size_t i = (size_t)blockIdx.x * 256 + threadIdx.x;
    int c0 = (int)((i & 31) << 3);
    bf16x8 av = ((const bf16x8*)A)[i];
    bf16x8 bv = ((const bf16x8*)Bq)[i];
    bf16x8 o;
    #pragma unroll
    for (int e = 0; e < 8; ++e) {
        int c = c0 + e;
        float m1 = st[c] * invN;
        float v1 = fmaxf(st[256 + c] * invN - m1 * m1, 0.f);
        float m2 = st[512 + c] * invN;
        float v2 = fmaxf(st[768 + c] * invN - m2 * m2, 0.f);
        float y1 = gl[c] * (bf2f(av[e]) - m1) * rsqrtf(v1 + 1e-5f) + bl[c];
        float y2 = ga[c] * (bf2f(bv[e]) - m2) * rsqrtf(v2 + 1e-5f) + ba[c];
        o[e] = f2bf(y1 + y2);
    }
    ((bf16x8*)H)[i] = o;
}

// ---------------------------------------------------------------------------
// out(f32) = BN(X bf16; g,b,st)
// ---------------------------------------------------------------------------
__global__ __launch_bounds__(256) void bn_apply(
    const short* __restrict__ X, const float* __restrict__ g,
    const float* __restrict__ bb, const float* __restrict__ st,
    float* __restrict__ out, int n)
{
    const float invN = 1.0f / (float)n;
    size_t i = (size_t)blockIdx.x * 256 + threadIdx.x;
    int c0 = (int)((i & 31) << 3);
    bf16x8 xv = ((const bf16x8*)X)[i];
    float r[8];
    #pragma unroll
    for (int e = 0; e < 8; ++e) {
        int c = c0 + e;
        float m = st[c] * invN;
        float v = fmaxf(st[256 + c] * invN - m * m, 0.f);
        r[e] = g[c] * (bf2f(xv[e]) - m) * rsqrtf(v + 1e-5f) + bb[c];
    }
    float4 o0 = {r[0], r[1], r[2], r[3]};
    float4 o1 = {r[4], r[5], r[6], r[7]};
    ((float4*)out)[i * 2]     = o0;
    ((float4*)out)[i * 2 + 1] = o1;
}

// ---------------------------------------------------------------------------
extern "C" void kernel_launch(void* const* d_in, const int* in_sizes, int n_in,
                              void* d_out, int out_size, void* d_ws, size_t ws_size,
                              hipStream_t stream)
{
    const float* x    = (const float*)d_in[0];
    const int*   ei   = (const int*)d_in[1];
    const float* ea   = (const float*)d_in[2];
    const float* gw1  = (const float*)d_in[3];
    const float* gb1  = (const float*)d_in[4];
    const float* gw2  = (const float*)d_in[5];
    const float* gb2  = (const float*)d_in[6];
    const float* inw  = (const float*)d_in[7];
    const float* inb  = (const float*)d_in[8];
    const float* outw = (const float*)d_in[9];
    const float* outb = (const float*)d_in[10];
    const float* g1l  = (const float*)d_in[11];
    const float* b1l  = (const float*)d_in[12];
    const float* g1a  = (const float*)d_in[13];
    const float* b1a  = (const float*)d_in[14];
    const float* fw1  = (const float*)d_in[15];
    const float* fb1  = (const float*)d_in[16];
    const float* fw2  = (const float*)d_in[17];
    const float* fb2  = (const float*)d_in[18];
    const float* g2   = (const float*)d_in[19];
    const float* b2   = (const float*)d_in[20];
    float* out = (float*)d_out;

    const int N = in_sizes[0] / D;   // 32768
    const int E = in_sizes[1] / 2;   // 262144
    const size_t ND = (size_t)N * D;

    // ---- workspace: 5 bf16 N*D slots + weights + stats + CSR ----
    short* Bp = (short*)d_ws;
    short* S0 = Bp;                  // Zb -> QKV[0] -> F1b (attn-branch BN input)
    short* S1 = Bp + ND;             // T1b -> QKV[1] -> Hcb
    short* S2 = Bp + 2 * ND;         // QKV[2] -> FFHb[0]
    short* S3 = Bp + 3 * ND;         // F0b (local-branch BN input) -> FFHb[1]
    short* S4 = Bp + 4 * ND;         // Ob -> Gb (ff2 out)
    short* Wb = Bp + 5 * ND;         // 655360 shorts of bf16 weights
    short* gw1b = Wb, *gw2b = Wb + 65536, *inwb = Wb + 131072;
    short* outwb = Wb + 327680, *fw1b = Wb + 393216, *fw2b = Wb + 524288;
    float* st = (float*)(Wb + 655360);
    int* cnt    = (int*)(st + 1536);     // contiguous with st -> single memset
    int* excl   = cnt + N;
    int* rowptr = excl + N;
    int* ofs    = rowptr + N;
    int* bsum   = ofs + N;
    int* eord   = bsum + 256;
    int* esrc   = eord + E;

    const int GR = N / 128;          // 256 row-blocks
    const int EB = (E + 255) / 256;

    cvt_weights<<<320, 256, 0, stream>>>(gw1, gw2, inw, outw, fw1, fw2, Wb);

    // ---- CSR build (st + cnt zeroed in one memset) ----
    hipMemsetAsync(st, 0, (1536 + (size_t)N) * sizeof(int), stream);
    hist_kernel<<<EB, 256, 0, stream>>>(ei + E, cnt, E);
    scan_block<<<N / 256, 256, 0, stream>>>(cnt, excl, bsum);
    scan_bsum<<<1, 128, 0, stream>>>(bsum);
    scan_add<<<N / 256, 256, 0, stream>>>(excl, bsum, rowptr, ofs);
    scatter_kernel<<<EB, 256, 0, stream>>>(ei, ei + E, ofs, eord, esrc, E);

    // ---- local branch: Z -> gin1 -> gin2(+x, stats[0]) ----
    csr_aggr<<<(N * 64) / 256, 256, 0, stream>>>(x, ea, rowptr, cnt, eord, esrc, S0);
    gemm_mfma<false, true , false, false, false, false><<<dim3(2, GR), 256, 0, stream>>>(
        S0, nullptr, gw1b, gb1, nullptr, nullptr, S1, nullptr, 256, 256);
    gemm_mfma<false, false, true , false, true , false><<<dim3(2, GR), 256, 0, stream>>>(
        S1, nullptr, gw2b, gb2, x, nullptr, S3, st, 256, 256);

    // ---- global branch: QKV(f32 x, Q pre-scaled) -> attn -> outproj ----
    gemm_mfma<true , false, false, false, false, true ><<<dim3(6, GR), 256, 0, stream>>>(
        nullptr, x, inwb, inb, nullptr, nullptr, S0, nullptr, 256, 768);
    attn_mfma<<<(N / PG) * 8 * 8, 256, 0, stream>>>(S0, S4);
    gemm_mfma<false, false, true , false, true , false><<<dim3(2, GR), 256, 0, stream>>>(
        S4, nullptr, outwb, outb, x, nullptr, S0, st + 512, 256, 256);

    // ---- combine + FF (ff2: +Hc, stats[1024]) + final BN ----
    bn_combine<<<(unsigned)(ND / 8 / 256), 256, 0, stream>>>(
        S3, S0, g1l, b1l, g1a, b1a, st, S1, N);
    gemm_mfma<false, true , false, false, false, false><<<dim3(4, GR), 256, 0, stream>>>(
        S1, nullptr, fw1b, fb1, nullptr, nullptr, S2, nullptr, 256, 512);
    gemm_mfma<false, false, false, true , true , false><<<dim3(2, GR), 256, 0, stream>>>(
        S2, nullptr, fw2b, fb2, nullptr, S1, S4, st + 1024, 512, 256);
    bn_apply<<<(unsigned)(ND / 8 / 256), 256, 0, stream>>>(
        S4, g2, b2, st + 1024, out, N);
}